// Round 16
// baseline (384.267 us; speedup 1.0000x reference)
//
#include <hip/hip_runtime.h>
#include <hip/hip_bf16.h>

typedef float f32x4 __attribute__((ext_vector_type(4)));
typedef float f32x16 __attribute__((ext_vector_type(16)));
typedef unsigned short u16x8 __attribute__((ext_vector_type(8)));
typedef unsigned int u32x2 __attribute__((ext_vector_type(2)));
typedef unsigned int u32x4 __attribute__((ext_vector_type(4)));
typedef __bf16 b16x8 __attribute__((ext_vector_type(8)));

static __device__ __forceinline__ unsigned short f2bf(float f) {
    unsigned int u = __builtin_bit_cast(unsigned int, f);
    return (unsigned short)((u + 0x7fffu + ((u >> 16) & 1u)) >> 16);
}

static __device__ __forceinline__ float bf2f(unsigned short u) {
    return __builtin_bit_cast(float, (unsigned int)u << 16);
}

static __device__ __forceinline__ unsigned int pkbf(float a, float b) {
    unsigned short x = __builtin_bit_cast(unsigned short, (__bf16)a);
    unsigned short y = __builtin_bit_cast(unsigned short, (__bf16)b);
    return (unsigned int)x | ((unsigned int)y << 16);
}

static __device__ __forceinline__ f32x4 mfma16(u16x8 a, u16x8 b, f32x4 c) {
    return __builtin_amdgcn_mfma_f32_16x16x32_bf16(
        __builtin_bit_cast(b16x8, a), __builtin_bit_cast(b16x8, b), c, 0, 0, 0);
}

static __device__ __forceinline__ f32x16 mfma32(u16x8 a, u16x8 b, f32x16 c) {
    return __builtin_amdgcn_mfma_f32_32x32x16_bf16(
        __builtin_bit_cast(b16x8, a), __builtin_bit_cast(b16x8, b), c, 0, 0, 0);
}

// async global -> LDS, 16B per lane; LDS dest = wave-uniform base + lane*16
static __device__ __forceinline__ void gload16(const void* g, void* l) {
    __builtin_amdgcn_global_load_lds(
        (const __attribute__((address_space(1))) void*)g,
        (__attribute__((address_space(3))) void*)l, 16, 0, 0);
}

// ---------------- fused fp32 -> bf16 convert: x (2048 blocks) + Wq/Wk/Wv (512 each) ----------------
__global__ __launch_bounds__(256)
void convert_all(const float* __restrict__ x,
                 const float* __restrict__ wq, const float* __restrict__ wk,
                 const float* __restrict__ wv,
                 unsigned short* __restrict__ xb,
                 unsigned short* __restrict__ wqb, unsigned short* __restrict__ wkb,
                 unsigned short* __restrict__ wvb)
{
    const int bk = (int)blockIdx.x;
    const float* src;
    unsigned short* dst;
    int base;
    if (bk < 2048) { src = x; dst = xb; base = bk; }
    else {
        int wi = (bk - 2048) >> 9;
        src = (wi == 0) ? wq : (wi == 1) ? wk : wv;
        dst = (wi == 0) ? wqb : (wi == 1) ? wkb : wvb;
        base = (bk - 2048) & 511;
    }
    size_t i = ((size_t)base * 256 + threadIdx.x) * 8;
    f32x4 a = *reinterpret_cast<const f32x4*>(&src[i]);
    f32x4 b = *reinterpret_cast<const f32x4*>(&src[i + 4]);
    u16x8 r;
    r[0] = f2bf(a[0]); r[1] = f2bf(a[1]); r[2] = f2bf(a[2]); r[3] = f2bf(a[3]);
    r[4] = f2bf(b[0]); r[5] = f2bf(b[1]); r[6] = f2bf(b[2]); r[7] = f2bf(b[3]);
    *reinterpret_cast<u16x8*>(&dst[i]) = r;
}

// ---------------- QKV GEMM: global_load_lds staging (m97 structure) ----------------
// 128x128 tile, BK=32, 4 waves (2x2), wave tile 64x64. 768 blocks, supertile XCD swizzle.
// Weight segment per 1024 cols; segment 2 (V) writes output TRANSPOSED (V^T [1024][4096]).
__global__ __launch_bounds__(256)
void gemm_qkv(const unsigned short* __restrict__ A,
              const unsigned short* __restrict__ B0, const unsigned short* __restrict__ B1,
              const unsigned short* __restrict__ B2,
              const float* __restrict__ bias0, const float* __restrict__ bias1,
              const float* __restrict__ bias2,
              void* c0, void* c1, void* c2,
              int K, float scale0)
{
    __shared__ unsigned short As[128][32];
    __shared__ unsigned short Bs[128][32];
    const int t = (int)threadIdx.x;
    const int wave = t >> 6, lane = t & 63;
    const int wr = wave >> 1, wc = wave & 1;
    const int lo = lane & 15, g = lane >> 4;

    const int bid = (int)blockIdx.x;
    const int xc = bid & 7, c = bid >> 3;          // XCD xc, chunk-local c in [0,96)
    const int rowb = (xc >> 1) * 8 + (c & 7);
    const int colb = (xc & 1) * 12 + (c >> 3);
    const int brow = rowb * 128, bcol = colb * 128;
    const int w = bcol >> 10;
    const int segcol = bcol & 1023;
    const unsigned short* Bw = (w == 0) ? B0 : (w == 1) ? B1 : B2;
    const float* bi = (w == 0) ? bias0 : (w == 1) ? bias1 : bias2;
    const float scale = (w == 0) ? scale0 : 1.0f;

    // gload lane mapping: inst covers 16 rows x 64B; lane l -> row +(l>>2), chunk l&3
    const int glr = lane >> 2, glc = (lane & 3) * 8;

    f32x4 acc[4][4] = {};

    for (int kt = 0; kt < K; kt += 32) {
        __syncthreads();              // previous iteration's frag reads done
        #pragma unroll
        for (int i = 0; i < 2; ++i) {
            int r = wave * 32 + i * 16;
            gload16(&A[(size_t)(brow + r + glr) * K + kt + glc], &As[r][0]);
            gload16(&Bw[(size_t)(segcol + r + glr) * K + kt + glc], &Bs[r][0]);
        }
        __syncthreads();              // drains vmcnt -> tile ready

        u16x8 af[4], bf[4];
        #pragma unroll
        for (int mf = 0; mf < 4; ++mf)
            af[mf] = *reinterpret_cast<const u16x8*>(&As[wr * 64 + mf * 16 + lo][g * 8]);
        #pragma unroll
        for (int nf = 0; nf < 4; ++nf)
            bf[nf] = *reinterpret_cast<const u16x8*>(&Bs[wc * 64 + nf * 16 + lo][g * 8]);
        #pragma unroll
        for (int mf = 0; mf < 4; ++mf)
            #pragma unroll
            for (int nf = 0; nf < 4; ++nf)
                acc[mf][nf] = mfma16(af[mf], bf[nf], acc[mf][nf]);
    }

    void* cp = (w == 0) ? c0 : (w == 1) ? c1 : c2;
    #pragma unroll
    for (int nf = 0; nf < 4; ++nf) {
        int colLocal = wc * 64 + nf * 16 + lo;
        int cw = segcol + colLocal;
        float bv = bi[cw];
        if (w == 2) {
            #pragma unroll
            for (int mf = 0; mf < 4; ++mf) {
                int rowb2 = brow + wr * 64 + mf * 16 + g * 4;
                ushort4 u;
                u.x = f2bf(acc[mf][nf][0] + bv);
                u.y = f2bf(acc[mf][nf][1] + bv);
                u.z = f2bf(acc[mf][nf][2] + bv);
                u.w = f2bf(acc[mf][nf][3] + bv);
                *reinterpret_cast<ushort4*>(
                    &((unsigned short*)cp)[(size_t)cw * 4096 + rowb2]) = u;
            }
        } else {
            #pragma unroll
            for (int mf = 0; mf < 4; ++mf) {
                #pragma unroll
                for (int j = 0; j < 4; ++j) {
                    int row = brow + wr * 64 + mf * 16 + g * 4 + j;
                    ((unsigned short*)cp)[(size_t)row * 1024 + cw] =
                        f2bf((acc[mf][nf][j] + bv) * scale);
                }
            }
        }
    }
}

// ---------------- Wo GEMM: 128x64 tile, 512 blocks (2/CU), XCD supertile ----------------
__global__ __launch_bounds__(256)
void gemm_o(const unsigned short* __restrict__ A, const unsigned short* __restrict__ Bw,
            const float* __restrict__ bi, float* __restrict__ cp, int K)
{
    __shared__ unsigned short As[128][32];
    __shared__ unsigned short Bs[64][32];
    const int t = (int)threadIdx.x;
    const int wave = t >> 6, lane = t & 63;
    const int wr = wave >> 1, wc = wave & 1;
    const int lo = lane & 15, g = lane >> 4;
    const int bid = (int)blockIdx.x;
    const int xc = bid & 7, c = bid >> 3;          // c in [0,64)
    const int colb = (xc & 1) * 8 + (c & 7);
    const int rowb = (xc >> 1) * 8 + (c >> 3);
    const int brow = rowb * 128, bcol = colb * 64;

    const int row0 = t >> 2, c8 = t & 3;
    const int row1 = row0 + 64;

    f32x4 acc[4][2] = {};
    u16x8 aReg[2], bReg;

    aReg[0] = *reinterpret_cast<const u16x8*>(&A[(size_t)(brow + row0) * K + c8 * 8]);
    aReg[1] = *reinterpret_cast<const u16x8*>(&A[(size_t)(brow + row1) * K + c8 * 8]);
    bReg    = *reinterpret_cast<const u16x8*>(&Bw[(size_t)(bcol + row0) * K + c8 * 8]);

    for (int kt = 0; kt < K; kt += 32) {
        __syncthreads();
        *reinterpret_cast<u16x8*>(&As[row0][c8 * 8]) = aReg[0];
        *reinterpret_cast<u16x8*>(&As[row1][c8 * 8]) = aReg[1];
        *reinterpret_cast<u16x8*>(&Bs[row0][c8 * 8]) = bReg;
        __syncthreads();

        int ktn = kt + 32; if (ktn >= K) ktn = 0;   // wrap: harmless redundant load
        aReg[0] = *reinterpret_cast<const u16x8*>(&A[(size_t)(brow + row0) * K + ktn + c8 * 8]);
        aReg[1] = *reinterpret_cast<const u16x8*>(&A[(size_t)(brow + row1) * K + ktn + c8 * 8]);
        bReg    = *reinterpret_cast<const u16x8*>(&Bw[(size_t)(bcol + row0) * K + ktn + c8 * 8]);

        u16x8 af[4], bf[2];
        #pragma unroll
        for (int mf = 0; mf < 4; ++mf)
            af[mf] = *reinterpret_cast<const u16x8*>(&As[wr * 64 + mf * 16 + lo][g * 8]);
        #pragma unroll
        for (int nf = 0; nf < 2; ++nf)
            bf[nf] = *reinterpret_cast<const u16x8*>(&Bs[wc * 32 + nf * 16 + lo][g * 8]);
        #pragma unroll
        for (int mf = 0; mf < 4; ++mf)
            #pragma unroll
            for (int nf = 0; nf < 2; ++nf)
                acc[mf][nf] = mfma16(af[mf], bf[nf], acc[mf][nf]);
    }

    #pragma unroll
    for (int nf = 0; nf < 2; ++nf) {
        int cw = bcol + wc * 32 + nf * 16 + lo;
        float bv = bi[cw];
        #pragma unroll
        for (int mf = 0; mf < 4; ++mf)
            #pragma unroll
            for (int j = 0; j < 4; ++j) {
                int row = brow + wr * 64 + mf * 16 + g * 4 + j;
                cp[(size_t)row * 1024 + cw] = acc[mf][nf][j] + bv;
            }
    }
}

// ---------------- Flash attention: 64 q-rows/wave, split-K=4 (4 blocks/CU, 16 waves/CU) ----------------
// 32x32 swapped, no-max softmax, reg-prefetch staging (T14), XOR swizzle. Grid 1024.
__global__ __launch_bounds__(256, 4)
void attn_kernel(const unsigned short* __restrict__ Q,
                 const unsigned short* __restrict__ Kg,
                 const unsigned short* __restrict__ VTg,
                 unsigned short* __restrict__ Opb, float* __restrict__ Lp)
{
    __shared__ unsigned short lds[2][2][4096];   // [buf][K/V][64 rows x 64 cols]
    const int t = (int)threadIdx.x;
    const int lane = t & 63;
    const int q5 = lane & 31;
    const int hi = lane >> 5;
    const int bid = (int)blockIdx.x;
    const int sp = bid >> 8;                     // [0,4)
    const int inner = bid & 255;
    const int h = (inner & 7) | (((inner >> 3) & 1) << 3);   // 2 heads per XCD
    const int qb = inner >> 4;                   // [0,16)
    const int hc = h * 64;
    const int wv = t >> 6;
    const int qbaseA = qb * 256 + wv * 32;
    const int qbaseB = qbaseA + 128;
    const int kt0 = sp * 1024;
    const int NT = 16;                           // 1024 / 64

    const int sr = t >> 3, sch = t & 7;
    const int f0 = (sr ^ (sr >> 3)) & 7;
    const int scol0 = (sch ^ f0) * 8;
    const int scol1 = (sch ^ f0 ^ 4) * 8;
    const int sdst = sr * 64 + sch * 8;

    u16x8 qfA[4], qfB[4];
    #pragma unroll
    for (int kf = 0; kf < 4; ++kf) {
        qfA[kf] = *reinterpret_cast<const u16x8*>(
            &Q[(size_t)(qbaseA + q5) * 1024 + hc + kf * 16 + hi * 8]);
        qfB[kf] = *reinterpret_cast<const u16x8*>(
            &Q[(size_t)(qbaseB + q5) * 1024 + hc + kf * 16 + hi * 8]);
    }

    f32x16 oA0 = {}, oA1 = {}, oB0 = {}, oB1 = {};
    float lsumA = 0.f, lsumB = 0.f;

    // prologue: stage first tile into buf 0
    {
        u16x8 k0 = *reinterpret_cast<const u16x8*>(&Kg[(size_t)(kt0 + sr) * 1024 + hc + scol0]);
        u16x8 k1 = *reinterpret_cast<const u16x8*>(&Kg[(size_t)(kt0 + sr + 32) * 1024 + hc + scol1]);
        u16x8 v0 = *reinterpret_cast<const u16x8*>(&VTg[(size_t)(hc + sr) * 4096 + kt0 + scol0]);
        u16x8 v1 = *reinterpret_cast<const u16x8*>(&VTg[(size_t)(hc + sr + 32) * 4096 + kt0 + scol1]);
        *reinterpret_cast<u16x8*>(&lds[0][0][sdst]) = k0;
        *reinterpret_cast<u16x8*>(&lds[0][0][sdst + 2048]) = k1;
        *reinterpret_cast<u16x8*>(&lds[0][1][sdst]) = v0;
        *reinterpret_cast<u16x8*>(&lds[0][1][sdst + 2048]) = v1;
    }

    const int sz0 = (q5 ^ (q5 >> 3)) & 7;
    const int sz1 = sz0 ^ 4;
    int cur = 0;

    for (int tt = 0; tt < NT; ++tt) {
        __syncthreads();   // buf[cur] staged; buf[cur^1] readers done

        const int ktn = kt0 + (((tt + 1) & (NT - 1)) << 6);
        u16x8 kn0 = *reinterpret_cast<const u16x8*>(&Kg[(size_t)(ktn + sr) * 1024 + hc + scol0]);
        u16x8 kn1 = *reinterpret_cast<const u16x8*>(&Kg[(size_t)(ktn + sr + 32) * 1024 + hc + scol1]);
        u16x8 vn0 = *reinterpret_cast<const u16x8*>(&VTg[(size_t)(hc + sr) * 4096 + ktn + scol0]);
        u16x8 vn1 = *reinterpret_cast<const u16x8*>(&VTg[(size_t)(hc + sr + 32) * 4096 + ktn + scol1]);

        const unsigned short* Kb = lds[cur][0];
        const unsigned short* Vb = lds[cur][1];

        // S^T = K Q^T for both q-blocks; each K-frag read feeds 4 mfma
        f32x16 sA0 = {}, sA1 = {}, sB0 = {}, sB1 = {};
        #pragma unroll
        for (int kf = 0; kf < 4; ++kf) {
            int off0 = ((kf * 2 + hi) ^ sz0) * 8;
            int off1 = ((kf * 2 + hi) ^ sz1) * 8;
            u16x8 ka0 = *reinterpret_cast<const u16x8*>(&Kb[q5 * 64 + off0]);
            u16x8 ka1 = *reinterpret_cast<const u16x8*>(&Kb[(q5 + 32) * 64 + off1]);
            sA0 = mfma32(ka0, qfA[kf], sA0);
            sA1 = mfma32(ka1, qfA[kf], sA1);
            sB0 = mfma32(ka0, qfB[kf], sB0);
            sB1 = mfma32(ka1, qfB[kf], sB1);
        }

        // P = exp2(S), packed bf16; row sums (q-block A then B)
        unsigned int uA0[8], uA1[8], uB0[8], uB1[8];
        float psA = 0.f, psB = 0.f;
        #pragma unroll
        for (int r = 0; r < 8; ++r) {
            float e0 = __builtin_amdgcn_exp2f(sA0[2 * r]);
            float e1 = __builtin_amdgcn_exp2f(sA0[2 * r + 1]);
            float e2 = __builtin_amdgcn_exp2f(sA1[2 * r]);
            float e3 = __builtin_amdgcn_exp2f(sA1[2 * r + 1]);
            psA += (e0 + e1) + (e2 + e3);
            uA0[r] = pkbf(e0, e1);
            uA1[r] = pkbf(e2, e3);
        }
        #pragma unroll
        for (int r = 0; r < 8; ++r) {
            float e0 = __builtin_amdgcn_exp2f(sB0[2 * r]);
            float e1 = __builtin_amdgcn_exp2f(sB0[2 * r + 1]);
            float e2 = __builtin_amdgcn_exp2f(sB1[2 * r]);
            float e3 = __builtin_amdgcn_exp2f(sB1[2 * r + 1]);
            psB += (e0 + e1) + (e2 + e3);
            uB0[r] = pkbf(e0, e1);
            uB1[r] = pkbf(e2, e3);
        }
        psA += __shfl_xor(psA, 32);
        psB += __shfl_xor(psB, 32);
        lsumA += psA;
        lsumB += psB;

        // PV A-frags via permlane32_swap (distinct operands), both q-blocks
        u16x8 paA[4], paB[4];
        #pragma unroll
        for (int b2 = 0; b2 < 2; ++b2) {
            #pragma unroll
            for (int ks = 0; ks < 2; ++ks) {
                {
                    unsigned int x0 = b2 ? uA1[4 * ks]     : uA0[4 * ks];
                    unsigned int x1 = b2 ? uA1[4 * ks + 1] : uA0[4 * ks + 1];
                    unsigned int y0 = b2 ? uA1[4 * ks + 2] : uA0[4 * ks + 2];
                    unsigned int y1 = b2 ? uA1[4 * ks + 3] : uA0[4 * ks + 3];
                    u32x2 r0 = __builtin_amdgcn_permlane32_swap(x0, y0, false, false);
                    u32x2 r1 = __builtin_amdgcn_permlane32_swap(x1, y1, false, false);
                    u32x4 d;
                    d[0] = r0[0]; d[1] = r1[0]; d[2] = r0[1]; d[3] = r1[1];
                    paA[2 * b2 + ks] = __builtin_bit_cast(u16x8, d);
                }
                {
                    unsigned int x0 = b2 ? uB1[4 * ks]     : uB0[4 * ks];
                    unsigned int x1 = b2 ? uB1[4 * ks + 1] : uB0[4 * ks + 1];
                    unsigned int y0 = b2 ? uB1[4 * ks + 2] : uB0[4 * ks + 2];
                    unsigned int y1 = b2 ? uB1[4 * ks + 3] : uB0[4 * ks + 3];
                    u32x2 r0 = __builtin_amdgcn_permlane32_swap(x0, y0, false, false);
                    u32x2 r1 = __builtin_amdgcn_permlane32_swap(x1, y1, false, false);
                    u32x4 d;
                    d[0] = r0[0]; d[1] = r1[0]; d[2] = r0[1]; d[3] = r1[1];
                    paB[2 * b2 + ks] = __builtin_bit_cast(u16x8, d);
                }
            }
        }

        // O += P V : each V-frag read feeds 4 mfma
        #pragma unroll
        for (int ks = 0; ks < 4; ++ks) {
            int off0 = ((ks * 2 + hi) ^ sz0) * 8;
            int off1 = ((ks * 2 + hi) ^ sz1) * 8;
            u16x8 vb0 = *reinterpret_cast<const u16x8*>(&Vb[q5 * 64 + off0]);
            u16x8 vb1 = *reinterpret_cast<const u16x8*>(&Vb[(q5 + 32) * 64 + off1]);
            oA0 = mfma32(paA[ks], vb0, oA0);
            oA1 = mfma32(paA[ks], vb1, oA1);
            oB0 = mfma32(paB[ks], vb0, oB0);
            oB1 = mfma32(paB[ks], vb1, oB1);
        }

        // write-late staging into the other buffer
        unsigned short* Kw = lds[cur ^ 1][0];
        unsigned short* Vw = lds[cur ^ 1][1];
        *reinterpret_cast<u16x8*>(&Kw[sdst]) = kn0;
        *reinterpret_cast<u16x8*>(&Kw[sdst + 2048]) = kn1;
        *reinterpret_cast<u16x8*>(&Vw[sdst]) = vn0;
        *reinterpret_cast<u16x8*>(&Vw[sdst + 2048]) = vn1;
        cur ^= 1;
    }

    // epilogue: bf16 partials [sp][inner][256 rows][64]
    const int pb = (sp << 8) + (h * 16 + qb);
    unsigned short* opA = Opb + ((size_t)pb * 256 + wv * 32) * 64;
    unsigned short* opB = opA + (size_t)128 * 64;
    #pragma unroll
    for (int r = 0; r < 16; ++r) {
        int qr = (r & 3) + 8 * (r >> 2) + 4 * hi;
        opA[(size_t)qr * 64 + q5]      = f2bf(oA0[r]);
        opA[(size_t)qr * 64 + 32 + q5] = f2bf(oA1[r]);
        opB[(size_t)qr * 64 + q5]      = f2bf(oB0[r]);
        opB[(size_t)qr * 64 + 32 + q5] = f2bf(oB1[r]);
    }
    if (hi == 0) {
        Lp[(size_t)pb * 256 + wv * 32 + q5]       = lsumA;
        Lp[(size_t)pb * 256 + 128 + wv * 32 + q5] = lsumB;
    }
}

// ---------------- combine (512 blocks, 4 bf16 partials) + Wo convert (512 blocks) ----------------
__global__ __launch_bounds__(256)
void combine2(const unsigned short* __restrict__ Opb, const float* __restrict__ Lp,
              unsigned short* __restrict__ Ctx,
              const float* __restrict__ Wo, unsigned short* __restrict__ wob)
{
    const int bk = (int)blockIdx.x;
    const int t = (int)threadIdx.x;
    if (bk >= 512) {
        size_t i = ((size_t)(bk - 512) * 256 + t) * 8;
        f32x4 a = *reinterpret_cast<const f32x4*>(&Wo[i]);
        f32x4 b = *reinterpret_cast<const f32x4*>(&Wo[i + 4]);
        u16x8 r;
        r[0] = f2bf(a[0]); r[1] = f2bf(a[1]); r[2] = f2bf(a[2]); r[3] = f2bf(a[3]);
        r[4] = f2bf(b[0]); r[5] = f2bf(b[1]); r[6] = f2bf(b[2]); r[7] = f2bf(b[3]);
        *reinterpret_cast<u16x8*>(&wob[i]) = r;
        return;
    }
    const int pb = bk >> 1, half = bk & 1;       // pb = h*16+qb, inner in [0,256)
    const int h = pb >> 4, qb = pb & 15;
    const int r = t >> 1, dh = (t & 1) * 32;
    const int lrow = half * 128 + r;             // local row within pb (0..255)
    const size_t rowoff = (size_t)lrow * 64 + dh;
    const size_t spstr = (size_t)256 * 256 * 64; // sp stride in Opb elements
    const size_t base0 = (size_t)pb * 256 * 64 + rowoff;
    float l = 0.f;
    #pragma unroll
    for (int s = 0; s < 4; ++s)
        l += Lp[((size_t)(s * 256 + pb)) * 256 + lrow];
    const float inv = 1.f / l;
    const int row = qb * 256 + lrow;
    unsigned short* dst = &Ctx[(size_t)row * 1024 + h * 64 + dh];
    #pragma unroll
    for (int d = 0; d < 32; d += 8) {
        u16x8 p0 = *reinterpret_cast<const u16x8*>(&Opb[base0 + d]);
        u16x8 p1 = *reinterpret_cast<const u16x8*>(&Opb[base0 + spstr + d]);
        u16x8 p2 = *reinterpret_cast<const u16x8*>(&Opb[base0 + 2 * spstr + d]);
        u16x8 p3 = *reinterpret_cast<const u16x8*>(&Opb[base0 + 3 * spstr + d]);
        u16x8 o;
        #pragma unroll
        for (int j = 0; j < 8; ++j)
            o[j] = f2bf(((bf2f(p0[j]) + bf2f(p1[j])) + (bf2f(p2[j]) + bf2f(p3[j]))) * inv);
        *reinterpret_cast<u16x8*>(&dst[d]) = o;
    }
}

extern "C" void kernel_launch(void* const* d_in, const int* in_sizes, int n_in,
                              void* d_out, int out_size, void* d_ws, size_t ws_size,
                              hipStream_t stream)
{
    const float* x  = (const float*)d_in[0];
    const float* Wq = (const float*)d_in[1];
    const float* bq = (const float*)d_in[2];
    const float* Wk = (const float*)d_in[3];
    const float* bk = (const float*)d_in[4];
    const float* Wv = (const float*)d_in[5];
    const float* bv = (const float*)d_in[6];
    const float* Wo = (const float*)d_in[7];
    const float* bo = (const float*)d_in[8];
    float* out = (float*)d_out;

    const int S = 4096, HID = 1024;
    const size_t MB = 1u << 20;
    unsigned short* xb  = (unsigned short*)d_ws;          // [0,8MB); reused as ctx
    unsigned short* qws = xb + (size_t)S * HID;           // [8,16MB); later reused for wob
    unsigned short* kws = qws + (size_t)S * HID;          // [16,24MB)
    unsigned short* vtw = kws + (size_t)S * HID;          // [24,32MB) V^T [1024][4096]
    unsigned short* cws = xb;
    unsigned short* Opb = (unsigned short*)((char*)d_ws + 32 * MB); // [32,64MB): bf16 [4][256][256][64]
    float* Lp = (float*)((char*)d_ws + 64 * MB);          // [64,65MB): [4][256][256] f32
    // Weights overlay: wq/wk/wv live [convert, QKV-GEMM] inside the Opb region.
    unsigned short* wqb = (unsigned short*)((char*)d_ws + 32 * MB);
    unsigned short* wkb = wqb + (size_t)HID * HID;
    unsigned short* wvb = wkb + (size_t)HID * HID;        // ends 38MB (dead before attn writes)
    // Wo overlay: lives [combine2, Wo-GEMM] in the dead qws region.
    unsigned short* wob = qws;

    const float qscale = 0.125f * 1.44269504088896f;  // 1/sqrt(64) * log2(e)

    convert_all<<<3584, 256, 0, stream>>>(x, Wq, Wk, Wv, xb, wqb, wkb, wvb);

    // fused QKV projection, supertiled grid (768 = 8 XCD x 8 rows x 12 cols)
    gemm_qkv<<<768, 256, 0, stream>>>(xb, wqb, wkb, wvb, bq, bk, bv,
                                      qws, kws, vtw, HID, qscale);

    attn_kernel<<<1024, 256, 0, stream>>>(qws, kws, vtw, Opb, Lp);

    combine2<<<1024, 256, 0, stream>>>(Opb, Lp, cws, Wo, wob);

    // output projection: 128x64 tiles, 512 blocks (2/CU), XCD supertile
    gemm_o<<<512, 256, 0, stream>>>(cws, wob, bo, out, HID);
}

// Round 17
// 201.029 us; speedup vs baseline: 1.9115x; 1.9115x over previous
//
#include <hip/hip_runtime.h>
#include <hip/hip_bf16.h>

typedef float f32x4 __attribute__((ext_vector_type(4)));
typedef float f32x16 __attribute__((ext_vector_type(16)));
typedef unsigned short u16x8 __attribute__((ext_vector_type(8)));
typedef unsigned int u32x2 __attribute__((ext_vector_type(2)));
typedef unsigned int u32x4 __attribute__((ext_vector_type(4)));
typedef __bf16 b16x8 __attribute__((ext_vector_type(8)));

static __device__ __forceinline__ unsigned short f2bf(float f) {
    unsigned int u = __builtin_bit_cast(unsigned int, f);
    return (unsigned short)((u + 0x7fffu + ((u >> 16) & 1u)) >> 16);
}

static __device__ __forceinline__ float bf2f(unsigned short u) {
    return __builtin_bit_cast(float, (unsigned int)u << 16);
}

static __device__ __forceinline__ unsigned int pkbf(float a, float b) {
    unsigned short x = __builtin_bit_cast(unsigned short, (__bf16)a);
    unsigned short y = __builtin_bit_cast(unsigned short, (__bf16)b);
    return (unsigned int)x | ((unsigned int)y << 16);
}

static __device__ __forceinline__ f32x4 mfma16(u16x8 a, u16x8 b, f32x4 c) {
    return __builtin_amdgcn_mfma_f32_16x16x32_bf16(
        __builtin_bit_cast(b16x8, a), __builtin_bit_cast(b16x8, b), c, 0, 0, 0);
}

static __device__ __forceinline__ f32x16 mfma32(u16x8 a, u16x8 b, f32x16 c) {
    return __builtin_amdgcn_mfma_f32_32x32x16_bf16(
        __builtin_bit_cast(b16x8, a), __builtin_bit_cast(b16x8, b), c, 0, 0, 0);
}

// async global -> LDS, 16B per lane; LDS dest = wave-uniform base + lane*16
static __device__ __forceinline__ void gload16(const void* g, void* l) {
    __builtin_amdgcn_global_load_lds(
        (const __attribute__((address_space(1))) void*)g,
        (__attribute__((address_space(3))) void*)l, 16, 0, 0);
}

// ---------------- fused fp32 -> bf16 convert: x (2048 blocks) + Wq/Wk/Wv (512 each) ----------------
__global__ __launch_bounds__(256)
void convert_all(const float* __restrict__ x,
                 const float* __restrict__ wq, const float* __restrict__ wk,
                 const float* __restrict__ wv,
                 unsigned short* __restrict__ xb,
                 unsigned short* __restrict__ wqb, unsigned short* __restrict__ wkb,
                 unsigned short* __restrict__ wvb)
{
    const int bk = (int)blockIdx.x;
    const float* src;
    unsigned short* dst;
    int base;
    if (bk < 2048) { src = x; dst = xb; base = bk; }
    else {
        int wi = (bk - 2048) >> 9;
        src = (wi == 0) ? wq : (wi == 1) ? wk : wv;
        dst = (wi == 0) ? wqb : (wi == 1) ? wkb : wvb;
        base = (bk - 2048) & 511;
    }
    size_t i = ((size_t)base * 256 + threadIdx.x) * 8;
    f32x4 a = *reinterpret_cast<const f32x4*>(&src[i]);
    f32x4 b = *reinterpret_cast<const f32x4*>(&src[i + 4]);
    u16x8 r;
    r[0] = f2bf(a[0]); r[1] = f2bf(a[1]); r[2] = f2bf(a[2]); r[3] = f2bf(a[3]);
    r[4] = f2bf(b[0]); r[5] = f2bf(b[1]); r[6] = f2bf(b[2]); r[7] = f2bf(b[3]);
    *reinterpret_cast<u16x8*>(&dst[i]) = r;
}

// ---------------- QKV GEMM: global_load_lds staging (m97 structure) ----------------
// 128x128 tile, BK=32, 4 waves (2x2), wave tile 64x64. 768 blocks, supertile XCD swizzle.
// Weight segment per 1024 cols; segment 2 (V) writes output TRANSPOSED (V^T [1024][4096]).
__global__ __launch_bounds__(256)
void gemm_qkv(const unsigned short* __restrict__ A,
              const unsigned short* __restrict__ B0, const unsigned short* __restrict__ B1,
              const unsigned short* __restrict__ B2,
              const float* __restrict__ bias0, const float* __restrict__ bias1,
              const float* __restrict__ bias2,
              void* c0, void* c1, void* c2,
              int K, float scale0)
{
    __shared__ unsigned short As[128][32];
    __shared__ unsigned short Bs[128][32];
    const int t = (int)threadIdx.x;
    const int wave = t >> 6, lane = t & 63;
    const int wr = wave >> 1, wc = wave & 1;
    const int lo = lane & 15, g = lane >> 4;

    const int bid = (int)blockIdx.x;
    const int xc = bid & 7, c = bid >> 3;          // XCD xc, chunk-local c in [0,96)
    const int rowb = (xc >> 1) * 8 + (c & 7);
    const int colb = (xc & 1) * 12 + (c >> 3);
    const int brow = rowb * 128, bcol = colb * 128;
    const int w = bcol >> 10;
    const int segcol = bcol & 1023;
    const unsigned short* Bw = (w == 0) ? B0 : (w == 1) ? B1 : B2;
    const float* bi = (w == 0) ? bias0 : (w == 1) ? bias1 : bias2;
    const float scale = (w == 0) ? scale0 : 1.0f;

    // gload lane mapping: inst covers 16 rows x 64B; lane l -> row +(l>>2), chunk l&3
    const int glr = lane >> 2, glc = (lane & 3) * 8;

    f32x4 acc[4][4] = {};

    for (int kt = 0; kt < K; kt += 32) {
        __syncthreads();              // previous iteration's frag reads done
        #pragma unroll
        for (int i = 0; i < 2; ++i) {
            int r = wave * 32 + i * 16;
            gload16(&A[(size_t)(brow + r + glr) * K + kt + glc], &As[r][0]);
            gload16(&Bw[(size_t)(segcol + r + glr) * K + kt + glc], &Bs[r][0]);
        }
        __syncthreads();              // drains vmcnt -> tile ready

        u16x8 af[4], bf[4];
        #pragma unroll
        for (int mf = 0; mf < 4; ++mf)
            af[mf] = *reinterpret_cast<const u16x8*>(&As[wr * 64 + mf * 16 + lo][g * 8]);
        #pragma unroll
        for (int nf = 0; nf < 4; ++nf)
            bf[nf] = *reinterpret_cast<const u16x8*>(&Bs[wc * 64 + nf * 16 + lo][g * 8]);
        #pragma unroll
        for (int mf = 0; mf < 4; ++mf)
            #pragma unroll
            for (int nf = 0; nf < 4; ++nf)
                acc[mf][nf] = mfma16(af[mf], bf[nf], acc[mf][nf]);
    }

    void* cp = (w == 0) ? c0 : (w == 1) ? c1 : c2;
    #pragma unroll
    for (int nf = 0; nf < 4; ++nf) {
        int colLocal = wc * 64 + nf * 16 + lo;
        int cw = segcol + colLocal;
        float bv = bi[cw];
        if (w == 2) {
            #pragma unroll
            for (int mf = 0; mf < 4; ++mf) {
                int rowb2 = brow + wr * 64 + mf * 16 + g * 4;
                ushort4 u;
                u.x = f2bf(acc[mf][nf][0] + bv);
                u.y = f2bf(acc[mf][nf][1] + bv);
                u.z = f2bf(acc[mf][nf][2] + bv);
                u.w = f2bf(acc[mf][nf][3] + bv);
                *reinterpret_cast<ushort4*>(
                    &((unsigned short*)cp)[(size_t)cw * 4096 + rowb2]) = u;
            }
        } else {
            #pragma unroll
            for (int mf = 0; mf < 4; ++mf) {
                #pragma unroll
                for (int j = 0; j < 4; ++j) {
                    int row = brow + wr * 64 + mf * 16 + g * 4 + j;
                    ((unsigned short*)cp)[(size_t)row * 1024 + cw] =
                        f2bf((acc[mf][nf][j] + bv) * scale);
                }
            }
        }
    }
}

// ---------------- Wo GEMM: 128x64 tile, 512 blocks (2/CU), XCD supertile ----------------
__global__ __launch_bounds__(256)
void gemm_o(const unsigned short* __restrict__ A, const unsigned short* __restrict__ Bw,
            const float* __restrict__ bi, float* __restrict__ cp, int K)
{
    __shared__ unsigned short As[128][32];
    __shared__ unsigned short Bs[64][32];
    const int t = (int)threadIdx.x;
    const int wave = t >> 6, lane = t & 63;
    const int wr = wave >> 1, wc = wave & 1;
    const int lo = lane & 15, g = lane >> 4;
    const int bid = (int)blockIdx.x;
    const int xc = bid & 7, c = bid >> 3;          // c in [0,64)
    const int colb = (xc & 1) * 8 + (c & 7);
    const int rowb = (xc >> 1) * 8 + (c >> 3);
    const int brow = rowb * 128, bcol = colb * 64;

    const int row0 = t >> 2, c8 = t & 3;
    const int row1 = row0 + 64;

    f32x4 acc[4][2] = {};
    u16x8 aReg[2], bReg;

    aReg[0] = *reinterpret_cast<const u16x8*>(&A[(size_t)(brow + row0) * K + c8 * 8]);
    aReg[1] = *reinterpret_cast<const u16x8*>(&A[(size_t)(brow + row1) * K + c8 * 8]);
    bReg    = *reinterpret_cast<const u16x8*>(&Bw[(size_t)(bcol + row0) * K + c8 * 8]);

    for (int kt = 0; kt < K; kt += 32) {
        __syncthreads();
        *reinterpret_cast<u16x8*>(&As[row0][c8 * 8]) = aReg[0];
        *reinterpret_cast<u16x8*>(&As[row1][c8 * 8]) = aReg[1];
        *reinterpret_cast<u16x8*>(&Bs[row0][c8 * 8]) = bReg;
        __syncthreads();

        int ktn = kt + 32; if (ktn >= K) ktn = 0;   // wrap: harmless redundant load
        aReg[0] = *reinterpret_cast<const u16x8*>(&A[(size_t)(brow + row0) * K + ktn + c8 * 8]);
        aReg[1] = *reinterpret_cast<const u16x8*>(&A[(size_t)(brow + row1) * K + ktn + c8 * 8]);
        bReg    = *reinterpret_cast<const u16x8*>(&Bw[(size_t)(bcol + row0) * K + ktn + c8 * 8]);

        u16x8 af[4], bf[2];
        #pragma unroll
        for (int mf = 0; mf < 4; ++mf)
            af[mf] = *reinterpret_cast<const u16x8*>(&As[wr * 64 + mf * 16 + lo][g * 8]);
        #pragma unroll
        for (int nf = 0; nf < 2; ++nf)
            bf[nf] = *reinterpret_cast<const u16x8*>(&Bs[wc * 32 + nf * 16 + lo][g * 8]);
        #pragma unroll
        for (int mf = 0; mf < 4; ++mf)
            #pragma unroll
            for (int nf = 0; nf < 2; ++nf)
                acc[mf][nf] = mfma16(af[mf], bf[nf], acc[mf][nf]);
    }

    #pragma unroll
    for (int nf = 0; nf < 2; ++nf) {
        int cw = bcol + wc * 32 + nf * 16 + lo;
        float bv = bi[cw];
        #pragma unroll
        for (int mf = 0; mf < 4; ++mf)
            #pragma unroll
            for (int j = 0; j < 4; ++j) {
                int row = brow + wr * 64 + mf * 16 + g * 4 + j;
                cp[(size_t)row * 1024 + cw] = acc[mf][nf][j] + bv;
            }
    }
}

// ---------------- Flash attention: 64 q-rows/wave, split-K=2, KVBLK=128 ----------------
// Two 64-key sub-tiles per barrier (compute block identical to the proven round-15 code,
// run twice with LDS base offset sub*4096). Halves barrier count; staging regs 8x u16x8.
__global__ __launch_bounds__(256, 2)
void attn_kernel(const unsigned short* __restrict__ Q,
                 const unsigned short* __restrict__ Kg,
                 const unsigned short* __restrict__ VTg,
                 unsigned short* __restrict__ Opb, float* __restrict__ Lp)
{
    __shared__ unsigned short lds[2][2][8192];   // [buf][K/V][128 rows x 64 cols]
    const int t = (int)threadIdx.x;
    const int lane = t & 63;
    const int q5 = lane & 31;
    const int hi = lane >> 5;
    const int bid = (int)blockIdx.x;
    const int sp = bid >> 8;
    const int inner = bid & 255;
    const int h = (inner & 7) | (((inner >> 3) & 1) << 3);   // 2 heads per XCD
    const int qb = inner >> 4;                   // [0,16)
    const int hc = h * 64;
    const int wv = t >> 6;
    const int qbaseA = qb * 256 + wv * 32;
    const int qbaseB = qbaseA + 128;
    const int kt0 = sp * 2048;
    const int NT = 16;                           // 2048 / 128

    // staging: i in [0,4): idx = t + i*256, row = idx>>3 (0..127), ch = idx&7
    int srow[4], sgc[4], sds[4];
    #pragma unroll
    for (int i = 0; i < 4; ++i) {
        int idx = t + i * 256;
        int row = idx >> 3, ch = idx & 7;
        int fr = (row ^ (row >> 3)) & 7;
        srow[i] = row;
        sgc[i] = (ch ^ fr) * 8;
        sds[i] = row * 64 + ch * 8;
    }

    u16x8 qfA[4], qfB[4];
    #pragma unroll
    for (int kf = 0; kf < 4; ++kf) {
        qfA[kf] = *reinterpret_cast<const u16x8*>(
            &Q[(size_t)(qbaseA + q5) * 1024 + hc + kf * 16 + hi * 8]);
        qfB[kf] = *reinterpret_cast<const u16x8*>(
            &Q[(size_t)(qbaseB + q5) * 1024 + hc + kf * 16 + hi * 8]);
    }

    f32x16 oA0 = {}, oA1 = {}, oB0 = {}, oB1 = {};
    float lsumA = 0.f, lsumB = 0.f;

    // prologue: stage first 128-key tile into buf 0
    #pragma unroll
    for (int i = 0; i < 4; ++i) {
        int row = srow[i];
        u16x8 kv = *reinterpret_cast<const u16x8*>(
            &Kg[(size_t)(kt0 + row) * 1024 + hc + sgc[i]]);
        int hv = row >> 6, d = row & 63;
        u16x8 vv = *reinterpret_cast<const u16x8*>(
            &VTg[(size_t)(hc + d) * 4096 + kt0 + hv * 64 + sgc[i]]);
        *reinterpret_cast<u16x8*>(&lds[0][0][sds[i]]) = kv;
        *reinterpret_cast<u16x8*>(&lds[0][1][sds[i]]) = vv;
    }

    const int sz0 = (q5 ^ (q5 >> 3)) & 7;
    const int sz1 = sz0 ^ 4;
    int cur = 0;

    for (int tt = 0; tt < NT; ++tt) {
        __syncthreads();   // buf[cur] staged; buf[cur^1] readers done

        const int ktn = kt0 + (((tt + 1) & (NT - 1)) << 7);
        u16x8 kr[4], vr[4];
        #pragma unroll
        for (int i = 0; i < 4; ++i) {
            int row = srow[i];
            kr[i] = *reinterpret_cast<const u16x8*>(
                &Kg[(size_t)(ktn + row) * 1024 + hc + sgc[i]]);
            int hv = row >> 6, d = row & 63;
            vr[i] = *reinterpret_cast<const u16x8*>(
                &VTg[(size_t)(hc + d) * 4096 + ktn + hv * 64 + sgc[i]]);
        }

        #pragma unroll
        for (int sub = 0; sub < 2; ++sub) {
            const unsigned short* Kb = &lds[cur][0][sub * 4096];
            const unsigned short* Vb = &lds[cur][1][sub * 4096];

            // S^T = K Q^T for both q-blocks; each K-frag read feeds 4 mfma
            f32x16 sA0 = {}, sA1 = {}, sB0 = {}, sB1 = {};
            #pragma unroll
            for (int kf = 0; kf < 4; ++kf) {
                int off0 = ((kf * 2 + hi) ^ sz0) * 8;
                int off1 = ((kf * 2 + hi) ^ sz1) * 8;
                u16x8 ka0 = *reinterpret_cast<const u16x8*>(&Kb[q5 * 64 + off0]);
                u16x8 ka1 = *reinterpret_cast<const u16x8*>(&Kb[(q5 + 32) * 64 + off1]);
                sA0 = mfma32(ka0, qfA[kf], sA0);
                sA1 = mfma32(ka1, qfA[kf], sA1);
                sB0 = mfma32(ka0, qfB[kf], sB0);
                sB1 = mfma32(ka1, qfB[kf], sB1);
            }

            // P = exp2(S), packed bf16; row sums
            unsigned int uA0[8], uA1[8], uB0[8], uB1[8];
            float psA = 0.f, psB = 0.f;
            #pragma unroll
            for (int r = 0; r < 8; ++r) {
                float e0 = __builtin_amdgcn_exp2f(sA0[2 * r]);
                float e1 = __builtin_amdgcn_exp2f(sA0[2 * r + 1]);
                float e2 = __builtin_amdgcn_exp2f(sA1[2 * r]);
                float e3 = __builtin_amdgcn_exp2f(sA1[2 * r + 1]);
                psA += (e0 + e1) + (e2 + e3);
                uA0[r] = pkbf(e0, e1);
                uA1[r] = pkbf(e2, e3);
            }
            #pragma unroll
            for (int r = 0; r < 8; ++r) {
                float e0 = __builtin_amdgcn_exp2f(sB0[2 * r]);
                float e1 = __builtin_amdgcn_exp2f(sB0[2 * r + 1]);
                float e2 = __builtin_amdgcn_exp2f(sB1[2 * r]);
                float e3 = __builtin_amdgcn_exp2f(sB1[2 * r + 1]);
                psB += (e0 + e1) + (e2 + e3);
                uB0[r] = pkbf(e0, e1);
                uB1[r] = pkbf(e2, e3);
            }
            psA += __shfl_xor(psA, 32);
            psB += __shfl_xor(psB, 32);
            lsumA += psA;
            lsumB += psB;

            // PV A-frags via permlane32_swap (distinct operands), both q-blocks
            u16x8 paA[4], paB[4];
            #pragma unroll
            for (int b2 = 0; b2 < 2; ++b2) {
                #pragma unroll
                for (int ks = 0; ks < 2; ++ks) {
                    {
                        unsigned int x0 = b2 ? uA1[4 * ks]     : uA0[4 * ks];
                        unsigned int x1 = b2 ? uA1[4 * ks + 1] : uA0[4 * ks + 1];
                        unsigned int y0 = b2 ? uA1[4 * ks + 2] : uA0[4 * ks + 2];
                        unsigned int y1 = b2 ? uA1[4 * ks + 3] : uA0[4 * ks + 3];
                        u32x2 r0 = __builtin_amdgcn_permlane32_swap(x0, y0, false, false);
                        u32x2 r1 = __builtin_amdgcn_permlane32_swap(x1, y1, false, false);
                        u32x4 d;
                        d[0] = r0[0]; d[1] = r1[0]; d[2] = r0[1]; d[3] = r1[1];
                        paA[2 * b2 + ks] = __builtin_bit_cast(u16x8, d);
                    }
                    {
                        unsigned int x0 = b2 ? uB1[4 * ks]     : uB0[4 * ks];
                        unsigned int x1 = b2 ? uB1[4 * ks + 1] : uB0[4 * ks + 1];
                        unsigned int y0 = b2 ? uB1[4 * ks + 2] : uB0[4 * ks + 2];
                        unsigned int y1 = b2 ? uB1[4 * ks + 3] : uB0[4 * ks + 3];
                        u32x2 r0 = __builtin_amdgcn_permlane32_swap(x0, y0, false, false);
                        u32x2 r1 = __builtin_amdgcn_permlane32_swap(x1, y1, false, false);
                        u32x4 d;
                        d[0] = r0[0]; d[1] = r1[0]; d[2] = r0[1]; d[3] = r1[1];
                        paB[2 * b2 + ks] = __builtin_bit_cast(u16x8, d);
                    }
                }
            }

            // O += P V : each V-frag read feeds 4 mfma
            #pragma unroll
            for (int ks = 0; ks < 4; ++ks) {
                int off0 = ((ks * 2 + hi) ^ sz0) * 8;
                int off1 = ((ks * 2 + hi) ^ sz1) * 8;
                u16x8 vb0 = *reinterpret_cast<const u16x8*>(&Vb[q5 * 64 + off0]);
                u16x8 vb1 = *reinterpret_cast<const u16x8*>(&Vb[(q5 + 32) * 64 + off1]);
                oA0 = mfma32(paA[ks], vb0, oA0);
                oA1 = mfma32(paA[ks], vb1, oA1);
                oB0 = mfma32(paB[ks], vb0, oB0);
                oB1 = mfma32(paB[ks], vb1, oB1);
            }
        }

        // write-late staging into the other buffer
        unsigned short* Kw = lds[cur ^ 1][0];
        unsigned short* Vw = lds[cur ^ 1][1];
        #pragma unroll
        for (int i = 0; i < 4; ++i) {
            *reinterpret_cast<u16x8*>(&Kw[sds[i]]) = kr[i];
            *reinterpret_cast<u16x8*>(&Vw[sds[i]]) = vr[i];
        }
        cur ^= 1;
    }

    // epilogue: bf16 partials [sp][inner][256 rows][64]
    const int pb = (sp << 8) + (h * 16 + qb);
    unsigned short* opA = Opb + ((size_t)pb * 256 + wv * 32) * 64;
    unsigned short* opB = opA + (size_t)128 * 64;
    #pragma unroll
    for (int r = 0; r < 16; ++r) {
        int qr = (r & 3) + 8 * (r >> 2) + 4 * hi;
        opA[(size_t)qr * 64 + q5]      = f2bf(oA0[r]);
        opA[(size_t)qr * 64 + 32 + q5] = f2bf(oA1[r]);
        opB[(size_t)qr * 64 + q5]      = f2bf(oB0[r]);
        opB[(size_t)qr * 64 + 32 + q5] = f2bf(oB1[r]);
    }
    if (hi == 0) {
        Lp[(size_t)pb * 256 + wv * 32 + q5]       = lsumA;
        Lp[(size_t)pb * 256 + 128 + wv * 32 + q5] = lsumB;
    }
}

// ---------------- combine (512 blocks, bf16 partials) + Wo convert (512 blocks) ----------------
__global__ __launch_bounds__(256)
void combine2(const unsigned short* __restrict__ Opb, const float* __restrict__ Lp,
              unsigned short* __restrict__ Ctx,
              const float* __restrict__ Wo, unsigned short* __restrict__ wob)
{
    const int bk = (int)blockIdx.x;
    const int t = (int)threadIdx.x;
    if (bk >= 512) {
        size_t i = ((size_t)(bk - 512) * 256 + t) * 8;
        f32x4 a = *reinterpret_cast<const f32x4*>(&Wo[i]);
        f32x4 b = *reinterpret_cast<const f32x4*>(&Wo[i + 4]);
        u16x8 r;
        r[0] = f2bf(a[0]); r[1] = f2bf(a[1]); r[2] = f2bf(a[2]); r[3] = f2bf(a[3]);
        r[4] = f2bf(b[0]); r[5] = f2bf(b[1]); r[6] = f2bf(b[2]); r[7] = f2bf(b[3]);
        *reinterpret_cast<u16x8*>(&wob[i]) = r;
        return;
    }
    const int pb = bk >> 1, half = bk & 1;       // pb = h*16+qb
    const int h = pb >> 4, qb = pb & 15;
    const int r = t >> 1, dh = (t & 1) * 32;
    const int lrow = half * 128 + r;             // local row within pb (0..255)
    const size_t i0 = ((size_t)pb * 256 + lrow) * 64 + dh;
    const size_t i1 = ((size_t)(256 + pb) * 256 + lrow) * 64 + dh;
    const float l = Lp[(size_t)pb * 256 + lrow] + Lp[(size_t)(256 + pb) * 256 + lrow];
    const float inv = 1.f / l;
    const int row = qb * 256 + lrow;
    unsigned short* dst = &Ctx[(size_t)row * 1024 + h * 64 + dh];
    #pragma unroll
    for (int d = 0; d < 32; d += 8) {
        u16x8 a = *reinterpret_cast<const u16x8*>(&Opb[i0 + d]);
        u16x8 bq = *reinterpret_cast<const u16x8*>(&Opb[i1 + d]);
        u16x8 o;
        #pragma unroll
        for (int j = 0; j < 8; ++j)
            o[j] = f2bf((bf2f(a[j]) + bf2f(bq[j])) * inv);
        *reinterpret_cast<u16x8*>(&dst[d]) = o;
    }
}

extern "C" void kernel_launch(void* const* d_in, const int* in_sizes, int n_in,
                              void* d_out, int out_size, void* d_ws, size_t ws_size,
                              hipStream_t stream)
{
    const float* x  = (const float*)d_in[0];
    const float* Wq = (const float*)d_in[1];
    const float* bq = (const float*)d_in[2];
    const float* Wk = (const float*)d_in[3];
    const float* bk = (const float*)d_in[4];
    const float* Wv = (const float*)d_in[5];
    const float* bv = (const float*)d_in[6];
    const float* Wo = (const float*)d_in[7];
    const float* bo = (const float*)d_in[8];
    float* out = (float*)d_out;

    const int S = 4096, HID = 1024;
    const size_t MB = 1u << 20;
    unsigned short* xb  = (unsigned short*)d_ws;          // [0,8MB); reused as ctx
    unsigned short* qws = xb + (size_t)S * HID;           // [8,16MB); later reused for wob
    unsigned short* kws = qws + (size_t)S * HID;          // [16,24MB)
    unsigned short* vtw = kws + (size_t)S * HID;          // [24,32MB) V^T [1024][4096]
    unsigned short* cws = xb;
    unsigned short* Opb = (unsigned short*)((char*)d_ws + 32 * MB); // [32,48MB): bf16 [2][256][256][64]
    float* Lp = (float*)((char*)d_ws + 64 * MB);          // [64,64.5MB)
    // Weights overlay: wq/wk/wv live [convert, QKV-GEMM] inside the Opb region.
    unsigned short* wqb = (unsigned short*)((char*)d_ws + 32 * MB);
    unsigned short* wkb = wqb + (size_t)HID * HID;
    unsigned short* wvb = wkb + (size_t)HID * HID;        // ends 38MB (dead before attn writes)
    // Wo overlay: lives [combine2, Wo-GEMM] in the dead qws region.
    unsigned short* wob = qws;

    const float qscale = 0.125f * 1.44269504088896f;  // 1/sqrt(64) * log2(e)

    convert_all<<<3584, 256, 0, stream>>>(x, Wq, Wk, Wv, xb, wqb, wkb, wvb);

    // fused QKV projection, supertiled grid (768 = 8 XCD x 8 rows x 12 cols)
    gemm_qkv<<<768, 256, 0, stream>>>(xb, wqb, wkb, wvb, bq, bk, bv,
                                      qws, kws, vtw, HID, qscale);

    attn_kernel<<<512, 256, 0, stream>>>(qws, kws, vtw, Opb, Lp);

    combine2<<<1024, 256, 0, stream>>>(Opb, Lp, cws, Wo, wob);

    // output projection: 128x64 tiles, 512 blocks (2/CU), XCD supertile
    gemm_o<<<512, 256, 0, stream>>>(cws, wob, bo, out, HID);
}

// Round 18
// 158.595 us; speedup vs baseline: 2.4229x; 1.2676x over previous
//
#include <hip/hip_runtime.h>
#include <hip/hip_bf16.h>

typedef float f32x4 __attribute__((ext_vector_type(4)));
typedef float f32x16 __attribute__((ext_vector_type(16)));
typedef unsigned short u16x8 __attribute__((ext_vector_type(8)));
typedef unsigned int u32x2 __attribute__((ext_vector_type(2)));
typedef unsigned int u32x4 __attribute__((ext_vector_type(4)));
typedef __bf16 b16x8 __attribute__((ext_vector_type(8)));

static __device__ __forceinline__ unsigned short f2bf(float f) {
    unsigned int u = __builtin_bit_cast(unsigned int, f);
    return (unsigned short)((u + 0x7fffu + ((u >> 16) & 1u)) >> 16);
}

static __device__ __forceinline__ float bf2f(unsigned short u) {
    return __builtin_bit_cast(float, (unsigned int)u << 16);
}

static __device__ __forceinline__ unsigned int pkbf(float a, float b) {
    unsigned short x = __builtin_bit_cast(unsigned short, (__bf16)a);
    unsigned short y = __builtin_bit_cast(unsigned short, (__bf16)b);
    return (unsigned int)x | ((unsigned int)y << 16);
}

static __device__ __forceinline__ f32x4 mfma16(u16x8 a, u16x8 b, f32x4 c) {
    return __builtin_amdgcn_mfma_f32_16x16x32_bf16(
        __builtin_bit_cast(b16x8, a), __builtin_bit_cast(b16x8, b), c, 0, 0, 0);
}

static __device__ __forceinline__ f32x16 mfma32(u16x8 a, u16x8 b, f32x16 c) {
    return __builtin_amdgcn_mfma_f32_32x32x16_bf16(
        __builtin_bit_cast(b16x8, a), __builtin_bit_cast(b16x8, b), c, 0, 0, 0);
}

// async global -> LDS, 16B per lane; LDS dest = wave-uniform base + lane*16
static __device__ __forceinline__ void gload16(const void* g, void* l) {
    __builtin_amdgcn_global_load_lds(
        (const __attribute__((address_space(1))) void*)g,
        (__attribute__((address_space(3))) void*)l, 16, 0, 0);
}

// ---------------- fused fp32 -> bf16 convert: x (2048 blocks) + Wq/Wk/Wv (512 each) ----------------
__global__ __launch_bounds__(256)
void convert_all(const float* __restrict__ x,
                 const float* __restrict__ wq, const float* __restrict__ wk,
                 const float* __restrict__ wv,
                 unsigned short* __restrict__ xb,
                 unsigned short* __restrict__ wqb, unsigned short* __restrict__ wkb,
                 unsigned short* __restrict__ wvb)
{
    const int bk = (int)blockIdx.x;
    const float* src;
    unsigned short* dst;
    int base;
    if (bk < 2048) { src = x; dst = xb; base = bk; }
    else {
        int wi = (bk - 2048) >> 9;
        src = (wi == 0) ? wq : (wi == 1) ? wk : wv;
        dst = (wi == 0) ? wqb : (wi == 1) ? wkb : wvb;
        base = (bk - 2048) & 511;
    }
    size_t i = ((size_t)base * 256 + threadIdx.x) * 8;
    f32x4 a = *reinterpret_cast<const f32x4*>(&src[i]);
    f32x4 b = *reinterpret_cast<const f32x4*>(&src[i + 4]);
    u16x8 r;
    r[0] = f2bf(a[0]); r[1] = f2bf(a[1]); r[2] = f2bf(a[2]); r[3] = f2bf(a[3]);
    r[4] = f2bf(b[0]); r[5] = f2bf(b[1]); r[6] = f2bf(b[2]); r[7] = f2bf(b[3]);
    *reinterpret_cast<u16x8*>(&dst[i]) = r;
}

// ---------------- QKV GEMM: global_load_lds staging (m97 structure) ----------------
// 128x128 tile, BK=32, 4 waves (2x2), wave tile 64x64. 768 blocks, supertile XCD swizzle.
// Weight segment per 1024 cols; segment 2 (V) writes output TRANSPOSED (V^T [1024][4096]).
__global__ __launch_bounds__(256)
void gemm_qkv(const unsigned short* __restrict__ A,
              const unsigned short* __restrict__ B0, const unsigned short* __restrict__ B1,
              const unsigned short* __restrict__ B2,
              const float* __restrict__ bias0, const float* __restrict__ bias1,
              const float* __restrict__ bias2,
              void* c0, void* c1, void* c2,
              int K, float scale0)
{
    __shared__ unsigned short As[128][32];
    __shared__ unsigned short Bs[128][32];
    const int t = (int)threadIdx.x;
    const int wave = t >> 6, lane = t & 63;
    const int wr = wave >> 1, wc = wave & 1;
    const int lo = lane & 15, g = lane >> 4;

    const int bid = (int)blockIdx.x;
    const int xc = bid & 7, c = bid >> 3;          // XCD xc, chunk-local c in [0,96)
    const int rowb = (xc >> 1) * 8 + (c & 7);
    const int colb = (xc & 1) * 12 + (c >> 3);
    const int brow = rowb * 128, bcol = colb * 128;
    const int w = bcol >> 10;
    const int segcol = bcol & 1023;
    const unsigned short* Bw = (w == 0) ? B0 : (w == 1) ? B1 : B2;
    const float* bi = (w == 0) ? bias0 : (w == 1) ? bias1 : bias2;
    const float scale = (w == 0) ? scale0 : 1.0f;

    // gload lane mapping: inst covers 16 rows x 64B; lane l -> row +(l>>2), chunk l&3
    const int glr = lane >> 2, glc = (lane & 3) * 8;

    f32x4 acc[4][4] = {};

    for (int kt = 0; kt < K; kt += 32) {
        __syncthreads();              // previous iteration's frag reads done
        #pragma unroll
        for (int i = 0; i < 2; ++i) {
            int r = wave * 32 + i * 16;
            gload16(&A[(size_t)(brow + r + glr) * K + kt + glc], &As[r][0]);
            gload16(&Bw[(size_t)(segcol + r + glr) * K + kt + glc], &Bs[r][0]);
        }
        __syncthreads();              // drains vmcnt -> tile ready

        u16x8 af[4], bf[4];
        #pragma unroll
        for (int mf = 0; mf < 4; ++mf)
            af[mf] = *reinterpret_cast<const u16x8*>(&As[wr * 64 + mf * 16 + lo][g * 8]);
        #pragma unroll
        for (int nf = 0; nf < 4; ++nf)
            bf[nf] = *reinterpret_cast<const u16x8*>(&Bs[wc * 64 + nf * 16 + lo][g * 8]);
        #pragma unroll
        for (int mf = 0; mf < 4; ++mf)
            #pragma unroll
            for (int nf = 0; nf < 4; ++nf)
                acc[mf][nf] = mfma16(af[mf], bf[nf], acc[mf][nf]);
    }

    void* cp = (w == 0) ? c0 : (w == 1) ? c1 : c2;
    #pragma unroll
    for (int nf = 0; nf < 4; ++nf) {
        int colLocal = wc * 64 + nf * 16 + lo;
        int cw = segcol + colLocal;
        float bv = bi[cw];
        if (w == 2) {
            #pragma unroll
            for (int mf = 0; mf < 4; ++mf) {
                int rowb2 = brow + wr * 64 + mf * 16 + g * 4;
                ushort4 u;
                u.x = f2bf(acc[mf][nf][0] + bv);
                u.y = f2bf(acc[mf][nf][1] + bv);
                u.z = f2bf(acc[mf][nf][2] + bv);
                u.w = f2bf(acc[mf][nf][3] + bv);
                *reinterpret_cast<ushort4*>(
                    &((unsigned short*)cp)[(size_t)cw * 4096 + rowb2]) = u;
            }
        } else {
            #pragma unroll
            for (int mf = 0; mf < 4; ++mf) {
                #pragma unroll
                for (int j = 0; j < 4; ++j) {
                    int row = brow + wr * 64 + mf * 16 + g * 4 + j;
                    ((unsigned short*)cp)[(size_t)row * 1024 + cw] =
                        f2bf((acc[mf][nf][j] + bv) * scale);
                }
            }
        }
    }
}

// ---------------- Wo GEMM: 128x64 tile, 512 blocks (2/CU), XCD supertile ----------------
__global__ __launch_bounds__(256)
void gemm_o(const unsigned short* __restrict__ A, const unsigned short* __restrict__ Bw,
            const float* __restrict__ bi, float* __restrict__ cp, int K)
{
    __shared__ unsigned short As[128][32];
    __shared__ unsigned short Bs[64][32];
    const int t = (int)threadIdx.x;
    const int wave = t >> 6, lane = t & 63;
    const int wr = wave >> 1, wc = wave & 1;
    const int lo = lane & 15, g = lane >> 4;
    const int bid = (int)blockIdx.x;
    const int xc = bid & 7, c = bid >> 3;          // c in [0,64)
    const int colb = (xc & 1) * 8 + (c & 7);
    const int rowb = (xc >> 1) * 8 + (c >> 3);
    const int brow = rowb * 128, bcol = colb * 64;

    const int row0 = t >> 2, c8 = t & 3;
    const int row1 = row0 + 64;

    f32x4 acc[4][2] = {};
    u16x8 aReg[2], bReg;

    aReg[0] = *reinterpret_cast<const u16x8*>(&A[(size_t)(brow + row0) * K + c8 * 8]);
    aReg[1] = *reinterpret_cast<const u16x8*>(&A[(size_t)(brow + row1) * K + c8 * 8]);
    bReg    = *reinterpret_cast<const u16x8*>(&Bw[(size_t)(bcol + row0) * K + c8 * 8]);

    for (int kt = 0; kt < K; kt += 32) {
        __syncthreads();
        *reinterpret_cast<u16x8*>(&As[row0][c8 * 8]) = aReg[0];
        *reinterpret_cast<u16x8*>(&As[row1][c8 * 8]) = aReg[1];
        *reinterpret_cast<u16x8*>(&Bs[row0][c8 * 8]) = bReg;
        __syncthreads();

        int ktn = kt + 32; if (ktn >= K) ktn = 0;   // wrap: harmless redundant load
        aReg[0] = *reinterpret_cast<const u16x8*>(&A[(size_t)(brow + row0) * K + ktn + c8 * 8]);
        aReg[1] = *reinterpret_cast<const u16x8*>(&A[(size_t)(brow + row1) * K + ktn + c8 * 8]);
        bReg    = *reinterpret_cast<const u16x8*>(&Bw[(size_t)(bcol + row0) * K + ktn + c8 * 8]);

        u16x8 af[4], bf[2];
        #pragma unroll
        for (int mf = 0; mf < 4; ++mf)
            af[mf] = *reinterpret_cast<const u16x8*>(&As[wr * 64 + mf * 16 + lo][g * 8]);
        #pragma unroll
        for (int nf = 0; nf < 2; ++nf)
            bf[nf] = *reinterpret_cast<const u16x8*>(&Bs[wc * 32 + nf * 16 + lo][g * 8]);
        #pragma unroll
        for (int mf = 0; mf < 4; ++mf)
            #pragma unroll
            for (int nf = 0; nf < 2; ++nf)
                acc[mf][nf] = mfma16(af[mf], bf[nf], acc[mf][nf]);
    }

    #pragma unroll
    for (int nf = 0; nf < 2; ++nf) {
        int cw = bcol + wc * 32 + nf * 16 + lo;
        float bv = bi[cw];
        #pragma unroll
        for (int mf = 0; mf < 4; ++mf)
            #pragma unroll
            for (int j = 0; j < 4; ++j) {
                int row = brow + wr * 64 + mf * 16 + g * 4 + j;
                cp[(size_t)row * 1024 + cw] = acc[mf][nf][j] + bv;
            }
    }
}

// ---------------- Flash attention: 64 q-rows/wave (2 q-blocks share each K/V frag read) ----------------
// 32x32 swapped, no-max softmax, reg-prefetch staging (T14), XOR swizzle, split-K=2.
// Block = 4 waves x 64 q = 256 q-rows, one head, half the keys. Grid 512.
__global__ __launch_bounds__(256, 2)
void attn_kernel(const unsigned short* __restrict__ Q,
                 const unsigned short* __restrict__ Kg,
                 const unsigned short* __restrict__ VTg,
                 unsigned short* __restrict__ Opb, float* __restrict__ Lp)
{
    __shared__ unsigned short lds[2][2][4096];   // [buf][K/V][64 rows x 64 cols]
    const int t = (int)threadIdx.x;
    const int lane = t & 63;
    const int q5 = lane & 31;
    const int hi = lane >> 5;
    const int bid = (int)blockIdx.x;
    const int sp = bid >> 8;
    const int inner = bid & 255;
    const int h = (inner & 7) | (((inner >> 3) & 1) << 3);   // 2 heads per XCD
    const int qb = inner >> 4;                   // [0,16)
    const int hc = h * 64;
    const int wv = t >> 6;
    const int qbaseA = qb * 256 + wv * 32;
    const int qbaseB = qbaseA + 128;
    const int kt0 = sp * 2048;
    const int NT = 32;                           // 2048 / 64

    const int sr = t >> 3, sch = t & 7;
    const int f0 = (sr ^ (sr >> 3)) & 7;          // swzfun(sr); swzfun(sr+32) = f0^4
    const int scol0 = (sch ^ f0) * 8;
    const int scol1 = (sch ^ f0 ^ 4) * 8;
    const int sdst = sr * 64 + sch * 8;

    u16x8 qfA[4], qfB[4];
    #pragma unroll
    for (int kf = 0; kf < 4; ++kf) {
        qfA[kf] = *reinterpret_cast<const u16x8*>(
            &Q[(size_t)(qbaseA + q5) * 1024 + hc + kf * 16 + hi * 8]);
        qfB[kf] = *reinterpret_cast<const u16x8*>(
            &Q[(size_t)(qbaseB + q5) * 1024 + hc + kf * 16 + hi * 8]);
    }

    f32x16 oA0 = {}, oA1 = {}, oB0 = {}, oB1 = {};
    float lsumA = 0.f, lsumB = 0.f;

    // prologue: stage first tile into buf 0
    {
        u16x8 k0 = *reinterpret_cast<const u16x8*>(&Kg[(size_t)(kt0 + sr) * 1024 + hc + scol0]);
        u16x8 k1 = *reinterpret_cast<const u16x8*>(&Kg[(size_t)(kt0 + sr + 32) * 1024 + hc + scol1]);
        u16x8 v0 = *reinterpret_cast<const u16x8*>(&VTg[(size_t)(hc + sr) * 4096 + kt0 + scol0]);
        u16x8 v1 = *reinterpret_cast<const u16x8*>(&VTg[(size_t)(hc + sr + 32) * 4096 + kt0 + scol1]);
        *reinterpret_cast<u16x8*>(&lds[0][0][sdst]) = k0;
        *reinterpret_cast<u16x8*>(&lds[0][0][sdst + 2048]) = k1;
        *reinterpret_cast<u16x8*>(&lds[0][1][sdst]) = v0;
        *reinterpret_cast<u16x8*>(&lds[0][1][sdst + 2048]) = v1;
    }

    const int sz0 = (q5 ^ (q5 >> 3)) & 7;
    const int sz1 = sz0 ^ 4;
    int cur = 0;

    for (int tt = 0; tt < NT; ++tt) {
        __syncthreads();   // buf[cur] staged; buf[cur^1] readers done

        const int ktn = kt0 + (((tt + 1) & (NT - 1)) << 6);
        u16x8 kn0 = *reinterpret_cast<const u16x8*>(&Kg[(size_t)(ktn + sr) * 1024 + hc + scol0]);
        u16x8 kn1 = *reinterpret_cast<const u16x8*>(&Kg[(size_t)(ktn + sr + 32) * 1024 + hc + scol1]);
        u16x8 vn0 = *reinterpret_cast<const u16x8*>(&VTg[(size_t)(hc + sr) * 4096 + ktn + scol0]);
        u16x8 vn1 = *reinterpret_cast<const u16x8*>(&VTg[(size_t)(hc + sr + 32) * 4096 + ktn + scol1]);

        const unsigned short* Kb = lds[cur][0];
        const unsigned short* Vb = lds[cur][1];

        // S^T = K Q^T for both q-blocks; each K-frag read feeds 4 mfma
        f32x16 sA0 = {}, sA1 = {}, sB0 = {}, sB1 = {};
        #pragma unroll
        for (int kf = 0; kf < 4; ++kf) {
            int off0 = ((kf * 2 + hi) ^ sz0) * 8;
            int off1 = ((kf * 2 + hi) ^ sz1) * 8;
            u16x8 ka0 = *reinterpret_cast<const u16x8*>(&Kb[q5 * 64 + off0]);
            u16x8 ka1 = *reinterpret_cast<const u16x8*>(&Kb[(q5 + 32) * 64 + off1]);
            sA0 = mfma32(ka0, qfA[kf], sA0);
            sA1 = mfma32(ka1, qfA[kf], sA1);
            sB0 = mfma32(ka0, qfB[kf], sB0);
            sB1 = mfma32(ka1, qfB[kf], sB1);
        }

        // P = exp2(S), packed bf16; row sums (q-block A then B)
        unsigned int uA0[8], uA1[8], uB0[8], uB1[8];
        float psA = 0.f, psB = 0.f;
        #pragma unroll
        for (int r = 0; r < 8; ++r) {
            float e0 = __builtin_amdgcn_exp2f(sA0[2 * r]);
            float e1 = __builtin_amdgcn_exp2f(sA0[2 * r + 1]);
            float e2 = __builtin_amdgcn_exp2f(sA1[2 * r]);
            float e3 = __builtin_amdgcn_exp2f(sA1[2 * r + 1]);
            psA += (e0 + e1) + (e2 + e3);
            uA0[r] = pkbf(e0, e1);
            uA1[r] = pkbf(e2, e3);
        }
        #pragma unroll
        for (int r = 0; r < 8; ++r) {
            float e0 = __builtin_amdgcn_exp2f(sB0[2 * r]);
            float e1 = __builtin_amdgcn_exp2f(sB0[2 * r + 1]);
            float e2 = __builtin_amdgcn_exp2f(sB1[2 * r]);
            float e3 = __builtin_amdgcn_exp2f(sB1[2 * r + 1]);
            psB += (e0 + e1) + (e2 + e3);
            uB0[r] = pkbf(e0, e1);
            uB1[r] = pkbf(e2, e3);
        }
        psA += __shfl_xor(psA, 32);
        psB += __shfl_xor(psB, 32);
        lsumA += psA;
        lsumB += psB;

        // PV A-frags via permlane32_swap (distinct operands), both q-blocks
        u16x8 paA[4], paB[4];
        #pragma unroll
        for (int b2 = 0; b2 < 2; ++b2) {
            #pragma unroll
            for (int ks = 0; ks < 2; ++ks) {
                {
                    unsigned int x0 = b2 ? uA1[4 * ks]     : uA0[4 * ks];
                    unsigned int x1 = b2 ? uA1[4 * ks + 1] : uA0[4 * ks + 1];
                    unsigned int y0 = b2 ? uA1[4 * ks + 2] : uA0[4 * ks + 2];
                    unsigned int y1 = b2 ? uA1[4 * ks + 3] : uA0[4 * ks + 3];
                    u32x2 r0 = __builtin_amdgcn_permlane32_swap(x0, y0, false, false);
                    u32x2 r1 = __builtin_amdgcn_permlane32_swap(x1, y1, false, false);
                    u32x4 d;
                    d[0] = r0[0]; d[1] = r1[0]; d[2] = r0[1]; d[3] = r1[1];
                    paA[2 * b2 + ks] = __builtin_bit_cast(u16x8, d);
                }
                {
                    unsigned int x0 = b2 ? uB1[4 * ks]     : uB0[4 * ks];
                    unsigned int x1 = b2 ? uB1[4 * ks + 1] : uB0[4 * ks + 1];
                    unsigned int y0 = b2 ? uB1[4 * ks + 2] : uB0[4 * ks + 2];
                    unsigned int y1 = b2 ? uB1[4 * ks + 3] : uB0[4 * ks + 3];
                    u32x2 r0 = __builtin_amdgcn_permlane32_swap(x0, y0, false, false);
                    u32x2 r1 = __builtin_amdgcn_permlane32_swap(x1, y1, false, false);
                    u32x4 d;
                    d[0] = r0[0]; d[1] = r1[0]; d[2] = r0[1]; d[3] = r1[1];
                    paB[2 * b2 + ks] = __builtin_bit_cast(u16x8, d);
                }
            }
        }

        // O += P V : each V-frag read feeds 4 mfma
        #pragma unroll
        for (int ks = 0; ks < 4; ++ks) {
            int off0 = ((ks * 2 + hi) ^ sz0) * 8;
            int off1 = ((ks * 2 + hi) ^ sz1) * 8;
            u16x8 vb0 = *reinterpret_cast<const u16x8*>(&Vb[q5 * 64 + off0]);
            u16x8 vb1 = *reinterpret_cast<const u16x8*>(&Vb[(q5 + 32) * 64 + off1]);
            oA0 = mfma32(paA[ks], vb0, oA0);
            oA1 = mfma32(paA[ks], vb1, oA1);
            oB0 = mfma32(paB[ks], vb0, oB0);
            oB1 = mfma32(paB[ks], vb1, oB1);
        }

        // write-late staging into the other buffer
        unsigned short* Kw = lds[cur ^ 1][0];
        unsigned short* Vw = lds[cur ^ 1][1];
        *reinterpret_cast<u16x8*>(&Kw[sdst]) = kn0;
        *reinterpret_cast<u16x8*>(&Kw[sdst + 2048]) = kn1;
        *reinterpret_cast<u16x8*>(&Vw[sdst]) = vn0;
        *reinterpret_cast<u16x8*>(&Vw[sdst + 2048]) = vn1;
        cur ^= 1;
    }

    // epilogue: bf16 partials [sp][pb][256 rows][64]
    const int pb = (sp << 8) + (h * 16 + qb);
    unsigned short* opA = Opb + ((size_t)pb * 256 + wv * 32) * 64;
    unsigned short* opB = opA + (size_t)128 * 64;
    #pragma unroll
    for (int r = 0; r < 16; ++r) {
        int qr = (r & 3) + 8 * (r >> 2) + 4 * hi;
        opA[(size_t)qr * 64 + q5]      = f2bf(oA0[r]);
        opA[(size_t)qr * 64 + 32 + q5] = f2bf(oA1[r]);
        opB[(size_t)qr * 64 + q5]      = f2bf(oB0[r]);
        opB[(size_t)qr * 64 + 32 + q5] = f2bf(oB1[r]);
    }
    if (hi == 0) {
        Lp[(size_t)pb * 256 + wv * 32 + q5]       = lsumA;
        Lp[(size_t)pb * 256 + 128 + wv * 32 + q5] = lsumB;
    }
}

// ---------------- combine (512 blocks, bf16 partials) + Wo convert (512 blocks) ----------------
__global__ __launch_bounds__(256)
void combine2(const unsigned short* __restrict__ Opb, const float* __restrict__ Lp,
              unsigned short* __restrict__ Ctx,
              const float* __restrict__ Wo, unsigned short* __restrict__ wob)
{
    const int bk = (int)blockIdx.x;
    const int t = (int)threadIdx.x;
    if (bk >= 512) {
        size_t i = ((size_t)(bk - 512) * 256 + t) * 8;
        f32x4 a = *reinterpret_cast<const f32x4*>(&Wo[i]);
        f32x4 b = *reinterpret_cast<const f32x4*>(&Wo[i + 4]);
        u16x8 r;
        r[0] = f2bf(a[0]); r[1] = f2bf(a[1]); r[2] = f2bf(a[2]); r[3] = f2bf(a[3]);
        r[4] = f2bf(b[0]); r[5] = f2bf(b[1]); r[6] = f2bf(b[2]); r[7] = f2bf(b[3]);
        *reinterpret_cast<u16x8*>(&wob[i]) = r;
        return;
    }
    const int pb = bk >> 1, half = bk & 1;       // pb = h*16+qb
    const int h = pb >> 4, qb = pb & 15;
    const int r = t >> 1, dh = (t & 1) * 32;
    const int lrow = half * 128 + r;             // local row within pb (0..255)
    const size_t i0 = ((size_t)pb * 256 + lrow) * 64 + dh;
    const size_t i1 = ((size_t)(256 + pb) * 256 + lrow) * 64 + dh;
    const float l = Lp[(size_t)pb * 256 + lrow] + Lp[(size_t)(256 + pb) * 256 + lrow];
    const float inv = 1.f / l;
    const int row = qb * 256 + lrow;
    unsigned short* dst = &Ctx[(size_t)row * 1024 + h * 64 + dh];
    #pragma unroll
    for (int d = 0; d < 32; d += 8) {
        u16x8 a = *reinterpret_cast<const u16x8*>(&Opb[i0 + d]);
        u16x8 bq = *reinterpret_cast<const u16x8*>(&Opb[i1 + d]);
        u16x8 o;
        #pragma unroll
        for (int j = 0; j < 8; ++j)
            o[j] = f2bf((bf2f(a[j]) + bf2f(bq[j])) * inv);
        *reinterpret_cast<u16x8*>(&dst[d]) = o;
    }
}

extern "C" void kernel_launch(void* const* d_in, const int* in_sizes, int n_in,
                              void* d_out, int out_size, void* d_ws, size_t ws_size,
                              hipStream_t stream)
{
    const float* x  = (const float*)d_in[0];
    const float* Wq = (const float*)d_in[1];
    const float* bq = (const float*)d_in[2];
    const float* Wk = (const float*)d_in[3];
    const float* bk = (const float*)d_in[4];
    const float* Wv = (const float*)d_in[5];
    const float* bv = (const float*)d_in[6];
    const float* Wo = (const float*)d_in[7];
    const float* bo = (const float*)d_in[8];
    float* out = (float*)d_out;

    const int S = 4096, HID = 1024;
    const size_t MB = 1u << 20;
    unsigned short* xb  = (unsigned short*)d_ws;          // [0,8MB); reused as ctx
    unsigned short* qws = xb + (size_t)S * HID;           // [8,16MB); later reused for wob
    unsigned short* kws = qws + (size_t)S * HID;          // [16,24MB)
    unsigned short* vtw = kws + (size_t)S * HID;          // [24,32MB) V^T [1024][4096]
    unsigned short* cws = xb;
    unsigned short* Opb = (unsigned short*)((char*)d_ws + 32 * MB); // [32,48MB): bf16 [2][256][256][64]
    float* Lp = (float*)((char*)d_ws + 64 * MB);          // [64,64.5MB)
    // Weights overlay: wq/wk/wv live [convert, QKV-GEMM] inside the Opb region.
    unsigned short* wqb = (unsigned short*)((char*)d_ws + 32 * MB);
    unsigned short* wkb = wqb + (size_t)HID * HID;
    unsigned short* wvb = wkb + (size_t)HID * HID;        // ends 38MB (dead before attn writes)
    // Wo overlay: lives [combine2, Wo-GEMM] in the dead qws region.
    unsigned short* wob = qws;

    const float qscale = 0.125f * 1.44269504088896f;  // 1/sqrt(64) * log2(e)

    convert_all<<<3584, 256, 0, stream>>>(x, Wq, Wk, Wv, xb, wqb, wkb, wvb);

    // fused QKV projection, supertiled grid (768 = 8 XCD x 8 rows x 12 cols)
    gemm_qkv<<<768, 256, 0, stream>>>(xb, wqb, wkb, wvb, bq, bk, bv,
                                      qws, kws, vtw, HID, qscale);

    attn_kernel<<<512, 256, 0, stream>>>(qws, kws, vtw, Opb, Lp);

    combine2<<<1024, 256, 0, stream>>>(Opb, Lp, cws, Wo, wob);

    // output projection: 128x64 tiles, 512 blocks (2/CU), XCD supertile
    gemm_o<<<512, 256, 0, stream>>>(cws, wob, bo, out, HID);
}